// Round 8
// baseline (3389.449 us; speedup 1.0000x reference)
//
#include <hip/hip_runtime.h>
#include <math.h>

#define Hn 50
#define Dn 8
#define Tn 512
#define BB 4            // batch rows per block
#define KC 14           // k's per chunk (4 chunks x 14 = 56 >= 50)
#define NBLK (2048 / BB) // 512 blocks; at 128 VGPR all 4096 waves resident

__device__ __forceinline__ float sigmoidf_(float x) {
    return 1.0f / (1.0f + __expf(-x));
}
__device__ __forceinline__ float tanhf_(float x) {
    float a = fabsf(x);
    float e = __expf(-2.0f * a);
    float r = (1.0f - e) / (1.0f + e);
    return copysignf(r, x);
}
__device__ __forceinline__ float rlane(float v, int l) {
    return __int_as_float(__builtin_amdgcn_readlane(__float_as_int(v), l));
}

// Persistent 2-layer LSTM, designed for the 128-VGPR cap.
// Lesson of r1-r7: any design needing >128 regs ends at 1 wave/SIMD
// (latency-bound, 12% occupancy, ~14k cyc/step). Here: 8-wave blocks,
// wave = (k-chunk ch = w>>1 [KC=14], row-half rh = w&1), lane = cell
// owning gates {2rh, 2rh+1}. Weights 88 floats/thread; liveness ~118.
// __launch_bounds__(512,2) -> 128-reg cap (r2-verified) -> 4 waves/EU
// -> 2 blocks/CU -> barriers of one block hide under the other.
__global__ __launch_bounds__(512, 2) void lstm2_kernel(
    const float* __restrict__ x,
    const float* __restrict__ Wih0, const float* __restrict__ Whh0,
    const float* __restrict__ bih0, const float* __restrict__ bhh0,
    const float* __restrict__ Wih1, const float* __restrict__ Whh1,
    const float* __restrict__ bih1, const float* __restrict__ bhh1,
    const float* __restrict__ Wlin, const float* __restrict__ blin,
    float* __restrict__ out)
{
    const int tid  = threadIdx.x;       // 0..511
    const int b0   = blockIdx.x * BB;
    const int w    = tid >> 6;          // wave 0..7
    const int lane = tid & 63;          // cell (50..63 padding)
    const int ch   = w >> 1;            // k-chunk 0..3
    const int rh   = w & 1;             // row half: gates {2rh, 2rh+1}
    const int kb   = ch * KC;           // k base (0,14,28,42; max k=55)

    // LDS. h tiles: slot k*4+b holds h[k][b], padded to 256 (zeroed) so the
    // b128 tile read at lanes 50..63 stays in-bounds. gP[ch][row][b] gate
    // partials: b128 stores lane-stride-16B (cf), act reads lane-stride-1.
    __shared__ __align__(16) float h0s[256];
    __shared__ __align__(16) float h1s[256];
    __shared__ __align__(16) float gP[4][256][4];
    __shared__ float bsum0[256];
    __shared__ float bsum1[256];

    // ---- weight slices in registers: 2 gate-rows x 14 k x 3 mats + wx ----
    float wa[2][KC], wb[2][KC], wc[2][KC], wx[2][2];
    #pragma unroll
    for (int gi = 0; gi < 2; ++gi) {
        const int g = 2 * rh + gi;
        const int grow = g * Hn + lane;            // valid iff lane<50
        #pragma unroll
        for (int j = 0; j < KC; ++j) {
            const int k = kb + j;
            const bool ok = (lane < Hn) && (k < Hn);
            wa[gi][j] = ok ? Whh0[grow * Hn + k] : 0.f;
            wb[gi][j] = ok ? Wih1[grow * Hn + k] : 0.f;
            wc[gi][j] = ok ? Whh1[grow * Hn + k] : 0.f;
        }
        wx[gi][0] = (lane < Hn) ? Wih0[grow * Dn + 2 * ch]     : 0.f;
        wx[gi][1] = (lane < Hn) ? Wih0[grow * Dn + 2 * ch + 1] : 0.f;
    }

    // ---- one-time LDS init: biases (combined), zero h tiles ----
    if (tid < 256) {
        const int g = tid >> 6, c = tid & 63;
        bsum0[tid] = (c < Hn) ? (bih0[g * Hn + c] + bhh0[g * Hn + c]) : 0.f;
        bsum1[tid] = (c < Hn) ? (bih1[g * Hn + c] + bhh1[g * Hn + c]) : 0.f;
        h0s[tid] = 0.f;
        h1s[tid] = 0.f;
    }
    __syncthreads();

    // ---- activation mapping: tid<200 owns state (cell=tid>>2, b=tid&3) ----
    const int cA = tid >> 2, bA = tid & 3;
    const bool actT = (tid < Hn * BB);
    float c0 = 0.f, c1 = 0.f;

    const float* xwp = x + 2 * ch;     // this wave's two x columns

    for (int t = 0; t < Tn; ++t) {
        // issue x_t loads first; consumed at END of phase A (~latency cover)
        float2 xv0 = *(const float2*)(xwp + ((size_t)(b0 + 0) * Tn + t) * Dn);
        float2 xv1 = *(const float2*)(xwp + ((size_t)(b0 + 1) * Tn + t) * Dn);
        float2 xv2 = *(const float2*)(xwp + ((size_t)(b0 + 2) * Tn + t) * Dn);
        float2 xv3 = *(const float2*)(xwp + ((size_t)(b0 + 3) * Tn + t) * Dn);

        // ---- phase A: acc = Whh0 . h0 (chunk partial), then + Wih0 . x ----
        const float4 h0t = *(const float4*)&h0s[lane * 4];
        float acc[2][BB];
        #pragma unroll
        for (int gi = 0; gi < 2; ++gi)
            #pragma unroll
            for (int b = 0; b < BB; ++b) acc[gi][b] = 0.f;
        #pragma unroll
        for (int j = 0; j < KC; ++j) {
            const int kl = kb + j;
            const float h0 = rlane(h0t.x, kl);
            const float h1 = rlane(h0t.y, kl);
            const float h2 = rlane(h0t.z, kl);
            const float h3 = rlane(h0t.w, kl);
            #pragma unroll
            for (int gi = 0; gi < 2; ++gi) {
                acc[gi][0] += wa[gi][j] * h0;
                acc[gi][1] += wa[gi][j] * h1;
                acc[gi][2] += wa[gi][j] * h2;
                acc[gi][3] += wa[gi][j] * h3;
            }
        }
        #pragma unroll
        for (int gi = 0; gi < 2; ++gi) {
            acc[gi][0] += wx[gi][0] * xv0.x + wx[gi][1] * xv0.y;
            acc[gi][1] += wx[gi][0] * xv1.x + wx[gi][1] * xv1.y;
            acc[gi][2] += wx[gi][0] * xv2.x + wx[gi][1] * xv2.y;
            acc[gi][3] += wx[gi][0] * xv3.x + wx[gi][1] * xv3.y;
        }
        #pragma unroll
        for (int gi = 0; gi < 2; ++gi)
            *(float4*)&gP[ch][(2 * rh + gi) * 64 + lane][0] =
                make_float4(acc[gi][0], acc[gi][1], acc[gi][2], acc[gi][3]);
        __syncthreads();

        // ---- phase B: layer-0 activations (4 partials + bias per gate) ----
        if (actT) {
            float gv[4];
            #pragma unroll
            for (int g = 0; g < 4; ++g) {
                const int r = g * 64 + cA;
                gv[g] = (gP[0][r][bA] + gP[1][r][bA])
                      + (gP[2][r][bA] + gP[3][r][bA]) + bsum0[r];
            }
            const float iv = sigmoidf_(gv[0]);
            const float fv = sigmoidf_(gv[1]);
            const float gg = tanhf_(gv[2]);
            const float ov = sigmoidf_(gv[3]);
            c0 = fv * c0 + iv * gg;
            h0s[tid] = ov * tanhf_(c0);     // slot cA*4+bA == tid
        }
        __syncthreads();

        // ---- phase C: acc = Wih1 . h0new + Whh1 . h1old ----
        const float4 h0n = *(const float4*)&h0s[lane * 4];
        const float4 h1t = *(const float4*)&h1s[lane * 4];
        float acc2[2][BB];
        #pragma unroll
        for (int gi = 0; gi < 2; ++gi)
            #pragma unroll
            for (int b = 0; b < BB; ++b) acc2[gi][b] = 0.f;
        #pragma unroll
        for (int j = 0; j < KC; ++j) {
            const int kl = kb + j;
            const float n0 = rlane(h0n.x, kl);
            const float n1 = rlane(h0n.y, kl);
            const float n2 = rlane(h0n.z, kl);
            const float n3 = rlane(h0n.w, kl);
            const float o0 = rlane(h1t.x, kl);
            const float o1 = rlane(h1t.y, kl);
            const float o2 = rlane(h1t.z, kl);
            const float o3 = rlane(h1t.w, kl);
            #pragma unroll
            for (int gi = 0; gi < 2; ++gi) {
                acc2[gi][0] += wb[gi][j] * n0 + wc[gi][j] * o0;
                acc2[gi][1] += wb[gi][j] * n1 + wc[gi][j] * o1;
                acc2[gi][2] += wb[gi][j] * n2 + wc[gi][j] * o2;
                acc2[gi][3] += wb[gi][j] * n3 + wc[gi][j] * o3;
            }
        }
        #pragma unroll
        for (int gi = 0; gi < 2; ++gi)
            *(float4*)&gP[ch][(2 * rh + gi) * 64 + lane][0] =
                make_float4(acc2[gi][0], acc2[gi][1], acc2[gi][2], acc2[gi][3]);
        __syncthreads();

        // ---- phase D: layer-1 activations ----
        if (actT) {
            float gv[4];
            #pragma unroll
            for (int g = 0; g < 4; ++g) {
                const int r = g * 64 + cA;
                gv[g] = (gP[0][r][bA] + gP[1][r][bA])
                      + (gP[2][r][bA] + gP[3][r][bA]) + bsum1[r];
            }
            const float iv = sigmoidf_(gv[0]);
            const float fv = sigmoidf_(gv[1]);
            const float gg = tanhf_(gv[2]);
            const float ov = sigmoidf_(gv[3]);
            c1 = fv * c1 + iv * gg;
            h1s[tid] = ov * tanhf_(c1);
        }
        __syncthreads();
    }

    // ---- head: out[b] = h1_last . Wlin + blin ----
    if (tid < BB) {
        float o = blin[0];
        #pragma unroll
        for (int k = 0; k < Hn; ++k) o += Wlin[k] * h1s[k * 4 + tid];
        out[b0 + tid] = o;
    }
}

extern "C" void kernel_launch(void* const* d_in, const int* in_sizes, int n_in,
                              void* d_out, int out_size, void* d_ws, size_t ws_size,
                              hipStream_t stream) {
    const float* x    = (const float*)d_in[0];
    const float* Wih0 = (const float*)d_in[1];
    const float* Whh0 = (const float*)d_in[2];
    const float* bih0 = (const float*)d_in[3];
    const float* bhh0 = (const float*)d_in[4];
    const float* Wih1 = (const float*)d_in[5];
    const float* Whh1 = (const float*)d_in[6];
    const float* bih1 = (const float*)d_in[7];
    const float* bhh1 = (const float*)d_in[8];
    const float* Wlin = (const float*)d_in[9];
    const float* blin = (const float*)d_in[10];
    float* out = (float*)d_out;

    lstm2_kernel<<<NBLK, 512, 0, stream>>>(x, Wih0, Whh0, bih0, bhh0,
                                           Wih1, Whh1, bih1, bhh1,
                                           Wlin, blin, out);
}

// Round 9
// 1138.297 us; speedup vs baseline: 2.9776x; 2.9776x over previous
//
#include <hip/hip_runtime.h>
#include <math.h>

#define Hn 50
#define Dn 8
#define Tn 512
#define BB 8              // batch rows per block (M-tile 16, rows 8..15 pad)
#define NBLK 256          // 2048 / BB

typedef __attribute__((ext_vector_type(8))) short short8;   // 8 bf16 (4 VGPRs)
typedef __attribute__((ext_vector_type(4))) float f32x4;

__device__ __forceinline__ float sigmoidf_(float x) {
    return 1.0f / (1.0f + __expf(-x));
}
__device__ __forceinline__ float tanhf_(float x) {
    float a = fabsf(x);
    float e = __expf(-2.0f * a);
    float r = (1.0f - e) / (1.0f + e);
    return copysignf(r, x);
}
// fp32 -> bf16 (RNE), kept in short as the MFMA frag element
__device__ __forceinline__ short f2bf(float f) {
    unsigned u = __float_as_uint(f);
    unsigned r = (u + 0x7FFFu + ((u >> 16) & 1u)) >> 16;
    return (short)r;
}
__device__ __forceinline__ float bf2f(short s) {
    return __uint_as_float(((unsigned)(unsigned short)s) << 16);
}

// Persistent 2-layer LSTM on the MATRIX pipe.
// r5-r8 proved the scalar path is issue-bound at ~2,900 us (readlane+FMA
// invariant ~550 cyc/row/step). Here the matvecs are MFMA
// (16x16x32 bf16): layer0 gates = [h0 | x_t] (K=64 pad) x W0^T, layer1
// gates = [h0new | h1] (K=128 pad) x W1^T. Split-bf16 (hi+lo, 3 products)
// keeps dot-product error ~2^-16 rel. Wave w owns N-tiles 4w..4w+3
// (Npad=256 gate columns). B-frags (192 regs) feed ONLY MFMA, so AGPR
// residency is copy-free (unified file) — unlike r6's VALU-path tax.
// C/D layout (m89-verified): n = lane&15, m = (lane>>4)*4 + reg.
// A layout (m120-verified): A[m = lane&15][k = (lane>>4)*8 + j].
// B layout (mirror):        B[k = (lane>>4)*8 + j][n = lane&15].
__global__ __launch_bounds__(256, 1) void lstm2_kernel(
    const float* __restrict__ x,
    const float* __restrict__ Wih0, const float* __restrict__ Whh0,
    const float* __restrict__ bih0, const float* __restrict__ bhh0,
    const float* __restrict__ Wih1, const float* __restrict__ Whh1,
    const float* __restrict__ bih1, const float* __restrict__ bhh1,
    const float* __restrict__ Wlin, const float* __restrict__ blin,
    float* __restrict__ out)
{
    const int tid  = threadIdx.x;     // 0..255
    const int b0   = blockIdx.x * BB;
    const int w    = tid >> 6;        // wave 0..3 -> N-tiles 4w..4w+3
    const int lane = tid & 63;
    const int quad = lane >> 4;
    const int col  = lane & 15;

    // A-packs, bf16 as shorts. Inner dim padded 32->40 to break bank
    // aliasing on the b128 frag reads. idx(sg,s,m,k) = ((sg*S+s)*16+m)*40+k.
    // aP0: layer0 A = [h0 (k 0..49) | x (k 50..57) | 0]; S=2 ksteps.
    // aP1: layer1 A = [h0new (k 0..49) | 0 | h1 (k 64..113) | 0]; S=4.
    __shared__ __align__(16) short aP0[2 * 2 * 16 * 40];
    __shared__ __align__(16) short aP1[2 * 4 * 16 * 40];
    __shared__ __align__(16) float gLds[256 * 8];   // [n gate][b]
    __shared__ float bs0[256], bs1[256];
    __shared__ float h1f[Hn * 8];                   // fp32 h1 at t=Tn-1

    // ---- B-fragments in registers (loaded once; MFMA-only consumers) ----
    short8 B0[4][2][2];   // [tile][kstep][hi/lo]
    short8 B1[4][4][2];
    #pragma unroll
    for (int tt = 0; tt < 4; ++tt) {
        const int ng = (4 * w + tt) * 16 + col;     // gate column n
        #pragma unroll
        for (int s = 0; s < 2; ++s) {
            #pragma unroll
            for (int j = 0; j < 8; ++j) {
                const int k = 32 * s + quad * 8 + j;
                float v = 0.f;
                if (ng < 4 * Hn) {
                    if (k < Hn)            v = Whh0[ng * Hn + k];
                    else if (k < Hn + Dn)  v = Wih0[ng * Dn + (k - Hn)];
                }
                const short hi = f2bf(v);
                const short lo = f2bf(v - bf2f(hi));
                B0[tt][s][0][j] = hi;
                B0[tt][s][1][j] = lo;
            }
        }
        #pragma unroll
        for (int s = 0; s < 4; ++s) {
            #pragma unroll
            for (int j = 0; j < 8; ++j) {
                const int k = 32 * s + quad * 8 + j;
                float v = 0.f;
                if (ng < 4 * Hn) {
                    if (k < Hn)                     v = Wih1[ng * Hn + k];
                    else if (k >= 64 && k < 64+Hn)  v = Whh1[ng * Hn + (k - 64)];
                }
                const short hi = f2bf(v);
                const short lo = f2bf(v - bf2f(hi));
                B1[tt][s][0][j] = hi;
                B1[tt][s][1][j] = lo;
            }
        }
    }

    // ---- init: zero A-packs (pads must be 0), biases ----
    for (int i = tid; i < 2 * 2 * 16 * 40; i += 256) aP0[i] = 0;
    for (int i = tid; i < 2 * 4 * 16 * 40; i += 256) aP1[i] = 0;
    bs0[tid] = (tid < 4 * Hn) ? (bih0[tid] + bhh0[tid]) : 0.f;
    bs1[tid] = (tid < 4 * Hn) ? (bih1[tid] + bhh1[tid]) : 0.f;
    __syncthreads();

    // stage x(t=0) into aP0 (k = 50+d -> kstep 1, k32 = 18+d)
    if (tid < 64) {
        const int xb = tid >> 3, xd = tid & 7;
        const float f = x[((size_t)(b0 + xb) * Tn + 0) * Dn + xd];
        const short hi = f2bf(f), lo = f2bf(f - bf2f(hi));
        aP0[((0 * 2 + 1) * 16 + xb) * 40 + 18 + xd] = hi;
        aP0[((1 * 2 + 1) * 16 + xb) * 40 + 18 + xd] = lo;
    }
    __syncthreads();

    // ---- activation ownership: S1 = tid (cells 0..31), S2 = 256+tid ----
    const int cel1 = tid >> 3, bb = tid & 7;
    const int cel2 = 32 + (tid >> 3);
    const bool hasS2 = (tid < (Hn * 8 - 256));      // 144 threads
    float c0a = 0.f, c0b = 0.f, c1a = 0.f, c1b = 0.f;

    for (int t = 0; t < Tn; ++t) {
        // ================= phase A: layer-0 MFMA =================
        f32x4 D0[4];
        #pragma unroll
        for (int tt = 0; tt < 4; ++tt) { f32x4 z = {0.f,0.f,0.f,0.f}; D0[tt] = z; }
        #pragma unroll
        for (int s = 0; s < 2; ++s) {
            const short8 ahi = *(const short8*)&aP0[((0*2+s)*16 + col)*40 + quad*8];
            const short8 alo = *(const short8*)&aP0[((1*2+s)*16 + col)*40 + quad*8];
            #pragma unroll
            for (int tt = 0; tt < 4; ++tt) {
                D0[tt] = __builtin_amdgcn_mfma_f32_16x16x32_bf16(ahi, B0[tt][s][0], D0[tt], 0,0,0);
                D0[tt] = __builtin_amdgcn_mfma_f32_16x16x32_bf16(ahi, B0[tt][s][1], D0[tt], 0,0,0);
                D0[tt] = __builtin_amdgcn_mfma_f32_16x16x32_bf16(alo, B0[tt][s][0], D0[tt], 0,0,0);
            }
        }
        if (quad < 2) {                 // rows m = quad*4+r in 0..7 are real
            #pragma unroll
            for (int tt = 0; tt < 4; ++tt) {
                const int n = (4 * w + tt) * 16 + col;
                #pragma unroll
                for (int r = 0; r < 4; ++r)
                    gLds[n * 8 + quad * 4 + r] = D0[tt][r];
            }
        }
        __syncthreads();

        // ================= phase B: layer-0 activations =================
        {
            const float vi = gLds[(0*Hn + cel1)*8 + bb] + bs0[0*Hn + cel1];
            const float vf = gLds[(1*Hn + cel1)*8 + bb] + bs0[1*Hn + cel1];
            const float vg = gLds[(2*Hn + cel1)*8 + bb] + bs0[2*Hn + cel1];
            const float vo = gLds[(3*Hn + cel1)*8 + bb] + bs0[3*Hn + cel1];
            c0a = sigmoidf_(vf) * c0a + sigmoidf_(vi) * tanhf_(vg);
            const float h = sigmoidf_(vo) * tanhf_(c0a);
            const short hi = f2bf(h), lo = f2bf(h - bf2f(hi));
            const int s = cel1 >> 5, k32 = cel1 & 31;
            aP0[((0*2+s)*16 + bb)*40 + k32] = hi;
            aP0[((1*2+s)*16 + bb)*40 + k32] = lo;
            aP1[((0*4+s)*16 + bb)*40 + k32] = hi;
            aP1[((1*4+s)*16 + bb)*40 + k32] = lo;
        }
        if (hasS2) {
            const float vi = gLds[(0*Hn + cel2)*8 + bb] + bs0[0*Hn + cel2];
            const float vf = gLds[(1*Hn + cel2)*8 + bb] + bs0[1*Hn + cel2];
            const float vg = gLds[(2*Hn + cel2)*8 + bb] + bs0[2*Hn + cel2];
            const float vo = gLds[(3*Hn + cel2)*8 + bb] + bs0[3*Hn + cel2];
            c0b = sigmoidf_(vf) * c0b + sigmoidf_(vi) * tanhf_(vg);
            const float h = sigmoidf_(vo) * tanhf_(c0b);
            const short hi = f2bf(h), lo = f2bf(h - bf2f(hi));
            const int s = cel2 >> 5, k32 = cel2 & 31;
            aP0[((0*2+s)*16 + bb)*40 + k32] = hi;
            aP0[((1*2+s)*16 + bb)*40 + k32] = lo;
            aP1[((0*4+s)*16 + bb)*40 + k32] = hi;
            aP1[((1*4+s)*16 + bb)*40 + k32] = lo;
        }
        __syncthreads();

        // ================= phase C: layer-1 MFMA (+ x prefetch) =========
        float xnf = 0.f;
        if (tid < 64 && t + 1 < Tn)
            xnf = x[((size_t)(b0 + (tid >> 3)) * Tn + (t + 1)) * Dn + (tid & 7)];

        f32x4 D1[4];
        #pragma unroll
        for (int tt = 0; tt < 4; ++tt) { f32x4 z = {0.f,0.f,0.f,0.f}; D1[tt] = z; }
        #pragma unroll
        for (int s = 0; s < 4; ++s) {
            const short8 ahi = *(const short8*)&aP1[((0*4+s)*16 + col)*40 + quad*8];
            const short8 alo = *(const short8*)&aP1[((1*4+s)*16 + col)*40 + quad*8];
            #pragma unroll
            for (int tt = 0; tt < 4; ++tt) {
                D1[tt] = __builtin_amdgcn_mfma_f32_16x16x32_bf16(ahi, B1[tt][s][0], D1[tt], 0,0,0);
                D1[tt] = __builtin_amdgcn_mfma_f32_16x16x32_bf16(ahi, B1[tt][s][1], D1[tt], 0,0,0);
                D1[tt] = __builtin_amdgcn_mfma_f32_16x16x32_bf16(alo, B1[tt][s][0], D1[tt], 0,0,0);
            }
        }
        if (quad < 2) {
            #pragma unroll
            for (int tt = 0; tt < 4; ++tt) {
                const int n = (4 * w + tt) * 16 + col;
                #pragma unroll
                for (int r = 0; r < 4; ++r)
                    gLds[n * 8 + quad * 4 + r] = D1[tt][r];
            }
        }
        __syncthreads();

        // ================= phase D: layer-1 activations + x stage =======
        {
            const float vi = gLds[(0*Hn + cel1)*8 + bb] + bs1[0*Hn + cel1];
            const float vf = gLds[(1*Hn + cel1)*8 + bb] + bs1[1*Hn + cel1];
            const float vg = gLds[(2*Hn + cel1)*8 + bb] + bs1[2*Hn + cel1];
            const float vo = gLds[(3*Hn + cel1)*8 + bb] + bs1[3*Hn + cel1];
            c1a = sigmoidf_(vf) * c1a + sigmoidf_(vi) * tanhf_(vg);
            const float h = sigmoidf_(vo) * tanhf_(c1a);
            const short hi = f2bf(h), lo = f2bf(h - bf2f(hi));
            const int s = 2 + (cel1 >> 5), k32 = cel1 & 31;   // k = 64 + cell
            aP1[((0*4+s)*16 + bb)*40 + k32] = hi;
            aP1[((1*4+s)*16 + bb)*40 + k32] = lo;
            if (t == Tn - 1) h1f[cel1 * 8 + bb] = h;
        }
        if (hasS2) {
            const float vi = gLds[(0*Hn + cel2)*8 + bb] + bs1[0*Hn + cel2];
            const float vf = gLds[(1*Hn + cel2)*8 + bb] + bs1[1*Hn + cel2];
            const float vg = gLds[(2*Hn + cel2)*8 + bb] + bs1[2*Hn + cel2];
            const float vo = gLds[(3*Hn + cel2)*8 + bb] + bs1[3*Hn + cel2];
            c1b = sigmoidf_(vf) * c1b + sigmoidf_(vi) * tanhf_(vg);
            const float h = sigmoidf_(vo) * tanhf_(c1b);
            const short hi = f2bf(h), lo = f2bf(h - bf2f(hi));
            const int s = 2 + (cel2 >> 5), k32 = cel2 & 31;
            aP1[((0*4+s)*16 + bb)*40 + k32] = hi;
            aP1[((1*4+s)*16 + bb)*40 + k32] = lo;
            if (t == Tn - 1) h1f[cel2 * 8 + bb] = h;
        }
        if (tid < 64 && t + 1 < Tn) {
            const short hi = f2bf(xnf), lo = f2bf(xnf - bf2f(hi));
            aP0[((0*2+1)*16 + (tid >> 3))*40 + 18 + (tid & 7)] = hi;
            aP0[((1*2+1)*16 + (tid >> 3))*40 + 18 + (tid & 7)] = lo;
        }
        __syncthreads();
    }

    // ---- head: out[b] = h1_last . Wlin + blin (fp32 path via h1f) ----
    if (tid < BB) {
        float o = blin[0];
        #pragma unroll
        for (int k = 0; k < Hn; ++k) o += Wlin[k] * h1f[k * 8 + tid];
        out[b0 + tid] = o;
    }
}

extern "C" void kernel_launch(void* const* d_in, const int* in_sizes, int n_in,
                              void* d_out, int out_size, void* d_ws, size_t ws_size,
                              hipStream_t stream) {
    const float* x    = (const float*)d_in[0];
    const float* Wih0 = (const float*)d_in[1];
    const float* Whh0 = (const float*)d_in[2];
    const float* bih0 = (const float*)d_in[3];
    const float* bhh0 = (const float*)d_in[4];
    const float* Wih1 = (const float*)d_in[5];
    const float* Whh1 = (const float*)d_in[6];
    const float* bih1 = (const float*)d_in[7];
    const float* bhh1 = (const float*)d_in[8];
    const float* Wlin = (const float*)d_in[9];
    const float* blin = (const float*)d_in[10];
    float* out = (float*)d_out;

    lstm2_kernel<<<NBLK, 256, 0, stream>>>(x, Wih0, Whh0, bih0, bhh0,
                                           Wih1, Whh1, bih1, bhh1,
                                           Wlin, blin, out);
}

// Round 10
// 979.682 us; speedup vs baseline: 3.4597x; 1.1619x over previous
//
#include <hip/hip_runtime.h>
#include <math.h>

#define Hn 50
#define Dn 8
#define Tn 512
#define BB 8              // batch rows per block (M-tile 16, rows 8..15 pad)
#define NT 13             // N tiles: 13*16 = 208 >= 200 gate columns
#define NBLK 256          // 2048 / BB

typedef __attribute__((ext_vector_type(8))) short short8;   // 8 bf16 (4 VGPRs)
typedef __attribute__((ext_vector_type(4))) float f32x4;

__device__ __forceinline__ float fexp2_(float x) {
#if __has_builtin(__builtin_amdgcn_exp2f)
    return __builtin_amdgcn_exp2f(x);
#else
    return exp2f(x);
#endif
}
__device__ __forceinline__ float frcp_(float x) {
#if __has_builtin(__builtin_amdgcn_rcpf)
    return __builtin_amdgcn_rcpf(x);
#else
    return 1.0f / x;
#endif
}
// sigmoid = rcp(1 + 2^(-x*log2e)) : ~4 VALU. tanh = 2*sigmoid(2x) - 1.
__device__ __forceinline__ float sigmoidf_(float x) {
    return frcp_(1.0f + fexp2_(-1.44269504f * x));
}
__device__ __forceinline__ float tanhf_(float x) {
    return 2.0f * sigmoidf_(2.0f * x) - 1.0f;
}
__device__ __forceinline__ float bf2f(short s) {
    return __uint_as_float(((unsigned)(unsigned short)s) << 16);
}
// truncation split: v = hi + lo + O(2^-17 v); lo absorbs the chop error
__device__ __forceinline__ void split_bf(float v, short& hi, short& lo) {
    hi = (short)(__float_as_uint(v) >> 16);
    const float r = v - bf2f(hi);
    lo = (short)(__float_as_uint(r) >> 16);
}

// Persistent 2-layer LSTM on the matrix pipe (r9 skeleton, overheads cut):
//  - gate columns CELL-MAJOR (ng = 4*cell+gate): act phase reads all 4
//    gates of a cell with ONE ds_read_b128
//  - gate buffer m-major gLds[8][256]: stores bank = ng%32, 2-way free
//    (r9's n-major [n][8] stores were 8-way -> 4.2e7 conflict cycles)
//  - bias pre-loaded into the MFMA accumulator (D init = bias splat)
//  - fast sigmoid/tanh via v_exp/v_rcp; truncation-based hi/lo split
//  - 13 N-tiles (wave0: 4, waves1-3: 3) instead of 16
// Layouts (m89/m120-verified): C/D n=lane&15, m=(lane>>4)*4+reg;
// A[m=lane&15][k=(lane>>4)*8+j]; B[k=(lane>>4)*8+j][n=lane&15].
__global__ __launch_bounds__(256, 1) void lstm2_kernel(
    const float* __restrict__ x,
    const float* __restrict__ Wih0, const float* __restrict__ Whh0,
    const float* __restrict__ bih0, const float* __restrict__ bhh0,
    const float* __restrict__ Wih1, const float* __restrict__ Whh1,
    const float* __restrict__ bih1, const float* __restrict__ bhh1,
    const float* __restrict__ Wlin, const float* __restrict__ blin,
    float* __restrict__ out)
{
    const int tid  = threadIdx.x;     // 0..255
    const int b0   = blockIdx.x * BB;
    const int w    = tid >> 6;        // wave 0..3
    const int lane = tid & 63;
    const int quad = lane >> 4;
    const int col  = lane & 15;
    const int ntw   = (w == 0) ? 4 : 3;          // tiles this wave
    const int tbase = (w == 0) ? 0 : (3 * w + 1); // w0:0-3 w1:4-6 w2:7-9 w3:10-12

    // A-packs (bf16 as short), inner dim padded 32->40 (frag reads hit the
    // 1KB/instr bank floor). idx(sg,s,m,k32) = ((sg*S+s)*16+m)*40+k32.
    // aP0: layer0 A = [h0 k0..49 | x k50..57 | 0], S=2.
    // aP1: layer1 A = [h0new k0..49 | 0 | h1 k64..113 | 0], S=4.
    __shared__ __align__(16) short aP0[2 * 2 * 16 * 40];
    __shared__ __align__(16) short aP1[2 * 4 * 16 * 40];
    __shared__ __align__(16) float gLds[8][256];   // [m=batch][ng] cell-major
    __shared__ float h1f[Hn * 8];                  // fp32 h1 at t=Tn-1

    // ---- B-fragments + bias in registers (cell-major columns) ----
    short8 B0[4][2][2];   // [tile][kstep][hi/lo]
    short8 B1[4][4][2];
    float  bw0[4], bw1[4];
    #pragma unroll
    for (int tt = 0; tt < 4; ++tt) {
        const int ng = (tbase + tt) * 16 + col;    // cell-major column
        const int cl = ng >> 2, g = ng & 3;        // cell, gate
        const bool on = (tt < ntw) && (cl < Hn);
        const int grow = g * Hn + cl;              // row in weight matrices
        bw0[tt] = on ? (bih0[grow] + bhh0[grow]) : 0.f;
        bw1[tt] = on ? (bih1[grow] + bhh1[grow]) : 0.f;
        #pragma unroll
        for (int s = 0; s < 2; ++s)
            #pragma unroll
            for (int j = 0; j < 8; ++j) {
                const int k = 32 * s + quad * 8 + j;
                float v = 0.f;
                if (on) {
                    if (k < Hn)           v = Whh0[grow * Hn + k];
                    else if (k < Hn + Dn) v = Wih0[grow * Dn + (k - Hn)];
                }
                short hi, lo; split_bf(v, hi, lo);
                B0[tt][s][0][j] = hi; B0[tt][s][1][j] = lo;
            }
        #pragma unroll
        for (int s = 0; s < 4; ++s)
            #pragma unroll
            for (int j = 0; j < 8; ++j) {
                const int k = 32 * s + quad * 8 + j;
                float v = 0.f;
                if (on) {
                    if (k < Hn)                      v = Wih1[grow * Hn + k];
                    else if (k >= 64 && k < 64 + Hn) v = Whh1[grow * Hn + (k - 64)];
                }
                short hi, lo; split_bf(v, hi, lo);
                B1[tt][s][0][j] = hi; B1[tt][s][1][j] = lo;
            }
    }

    // ---- init: zero A-packs (pads must stay 0) ----
    for (int i = tid; i < 2 * 2 * 16 * 40; i += 256) aP0[i] = 0;
    for (int i = tid; i < 2 * 4 * 16 * 40; i += 256) aP1[i] = 0;
    __syncthreads();

    // stage x(t=0): k = 50+d -> kstep 1, k32 = 18+d
    if (tid < 64) {
        const int xb = tid >> 3, xd = tid & 7;
        const float f = x[((size_t)(b0 + xb) * Tn + 0) * Dn + xd];
        short hi, lo; split_bf(f, hi, lo);
        aP0[((0 * 2 + 1) * 16 + xb) * 40 + 18 + xd] = hi;
        aP0[((1 * 2 + 1) * 16 + xb) * 40 + 18 + xd] = lo;
    }
    __syncthreads();

    // ---- activation ownership: state1 = (cel1,bb), state2 = (cel2,bb) ----
    const int cel1 = tid >> 3, bb = tid & 7;
    const int cel2 = 32 + (tid >> 3);
    const bool hasS2 = (tid < (Hn * 8 - 256));     // 144 threads
    float c0a = 0.f, c0b = 0.f, c1a = 0.f, c1b = 0.f;

    for (int t = 0; t < Tn; ++t) {
        // ================= phase A: layer-0 MFMA =================
        f32x4 D0[4];
        #pragma unroll
        for (int tt = 0; tt < 4; ++tt) {
            f32x4 z = {bw0[tt], bw0[tt], bw0[tt], bw0[tt]};
            D0[tt] = z;
        }
        #pragma unroll
        for (int s = 0; s < 2; ++s) {
            const short8 ahi = *(const short8*)&aP0[((0*2+s)*16 + col)*40 + quad*8];
            const short8 alo = *(const short8*)&aP0[((1*2+s)*16 + col)*40 + quad*8];
            #pragma unroll
            for (int tt = 0; tt < 4; ++tt) {
                if (tt < ntw) {
                    D0[tt] = __builtin_amdgcn_mfma_f32_16x16x32_bf16(ahi, B0[tt][s][0], D0[tt], 0,0,0);
                    D0[tt] = __builtin_amdgcn_mfma_f32_16x16x32_bf16(ahi, B0[tt][s][1], D0[tt], 0,0,0);
                    D0[tt] = __builtin_amdgcn_mfma_f32_16x16x32_bf16(alo, B0[tt][s][0], D0[tt], 0,0,0);
                }
            }
        }
        if (quad < 2) {                 // real rows m = quad*4+r in 0..7
            #pragma unroll
            for (int tt = 0; tt < 4; ++tt)
                if (tt < ntw) {
                    const int n = (tbase + tt) * 16 + col;
                    #pragma unroll
                    for (int r = 0; r < 4; ++r)
                        gLds[quad * 4 + r][n] = D0[tt][r];   // bank=n%32, 2-way
                }
        }
        __syncthreads();

        // ================= phase B: layer-0 activations =================
        {
            const f32x4 gv = *(const f32x4*)&gLds[bb][4 * cel1];  // i,f,g,o
            c0a = sigmoidf_(gv.y) * c0a + sigmoidf_(gv.x) * tanhf_(gv.z);
            const float h = sigmoidf_(gv.w) * tanhf_(c0a);
            short hi, lo; split_bf(h, hi, lo);
            const int s = cel1 >> 5, k32 = cel1 & 31;
            aP0[((0*2+s)*16 + bb)*40 + k32] = hi;
            aP0[((1*2+s)*16 + bb)*40 + k32] = lo;
            aP1[((0*4+s)*16 + bb)*40 + k32] = hi;
            aP1[((1*4+s)*16 + bb)*40 + k32] = lo;
        }
        if (hasS2) {
            const f32x4 gv = *(const f32x4*)&gLds[bb][4 * cel2];
            c0b = sigmoidf_(gv.y) * c0b + sigmoidf_(gv.x) * tanhf_(gv.z);
            const float h = sigmoidf_(gv.w) * tanhf_(c0b);
            short hi, lo; split_bf(h, hi, lo);
            const int s = cel2 >> 5, k32 = cel2 & 31;
            aP0[((0*2+s)*16 + bb)*40 + k32] = hi;
            aP0[((1*2+s)*16 + bb)*40 + k32] = lo;
            aP1[((0*4+s)*16 + bb)*40 + k32] = hi;
            aP1[((1*4+s)*16 + bb)*40 + k32] = lo;
        }
        __syncthreads();

        // ================= phase C: layer-1 MFMA (+ x prefetch) =========
        float xnf = 0.f;
        if (tid < 64 && t + 1 < Tn)
            xnf = x[((size_t)(b0 + (tid >> 3)) * Tn + (t + 1)) * Dn + (tid & 7)];

        f32x4 D1[4];
        #pragma unroll
        for (int tt = 0; tt < 4; ++tt) {
            f32x4 z = {bw1[tt], bw1[tt], bw1[tt], bw1[tt]};
            D1[tt] = z;
        }
        #pragma unroll
        for (int s = 0; s < 4; ++s) {
            const short8 ahi = *(const short8*)&aP1[((0*4+s)*16 + col)*40 + quad*8];
            const short8 alo = *(const short8*)&aP1[((1*4+s)*16 + col)*40 + quad*8];
            #pragma unroll
            for (int tt = 0; tt < 4; ++tt) {
                if (tt < ntw) {
                    D1[tt] = __builtin_amdgcn_mfma_f32_16x16x32_bf16(ahi, B1[tt][s][0], D1[tt], 0,0,0);
                    D1[tt] = __builtin_amdgcn_mfma_f32_16x16x32_bf16(ahi, B1[tt][s][1], D1[tt], 0,0,0);
                    D1[tt] = __builtin_amdgcn_mfma_f32_16x16x32_bf16(alo, B1[tt][s][0], D1[tt], 0,0,0);
                }
            }
        }
        if (quad < 2) {
            #pragma unroll
            for (int tt = 0; tt < 4; ++tt)
                if (tt < ntw) {
                    const int n = (tbase + tt) * 16 + col;
                    #pragma unroll
                    for (int r = 0; r < 4; ++r)
                        gLds[quad * 4 + r][n] = D1[tt][r];
                }
        }
        __syncthreads();

        // ================= phase D: layer-1 activations + x stage =======
        {
            const f32x4 gv = *(const f32x4*)&gLds[bb][4 * cel1];
            c1a = sigmoidf_(gv.y) * c1a + sigmoidf_(gv.x) * tanhf_(gv.z);
            const float h = sigmoidf_(gv.w) * tanhf_(c1a);
            short hi, lo; split_bf(h, hi, lo);
            const int s = 2 + (cel1 >> 5), k32 = cel1 & 31;   // k = 64+cell
            aP1[((0*4+s)*16 + bb)*40 + k32] = hi;
            aP1[((1*4+s)*16 + bb)*40 + k32] = lo;
            if (t == Tn - 1) h1f[cel1 * 8 + bb] = h;
        }
        if (hasS2) {
            const f32x4 gv = *(const f32x4*)&gLds[bb][4 * cel2];
            c1b = sigmoidf_(gv.y) * c1b + sigmoidf_(gv.x) * tanhf_(gv.z);
            const float h = sigmoidf_(gv.w) * tanhf_(c1b);
            short hi, lo; split_bf(h, hi, lo);
            const int s = 2 + (cel2 >> 5), k32 = cel2 & 31;
            aP1[((0*4+s)*16 + bb)*40 + k32] = hi;
            aP1[((1*4+s)*16 + bb)*40 + k32] = lo;
            if (t == Tn - 1) h1f[cel2 * 8 + bb] = h;
        }
        if (tid < 64 && t + 1 < Tn) {
            short hi, lo; split_bf(xnf, hi, lo);
            aP0[((0*2+1)*16 + (tid >> 3))*40 + 18 + (tid & 7)] = hi;
            aP0[((1*2+1)*16 + (tid >> 3))*40 + 18 + (tid & 7)] = lo;
        }
        __syncthreads();
    }

    // ---- head: out[b] = h1_last . Wlin + blin (fp32 path) ----
    if (tid < BB) {
        float o = blin[0];
        #pragma unroll
        for (int k = 0; k < Hn; ++k) o += Wlin[k] * h1f[k * 8 + tid];
        out[b0 + tid] = o;
    }
}

extern "C" void kernel_launch(void* const* d_in, const int* in_sizes, int n_in,
                              void* d_out, int out_size, void* d_ws, size_t ws_size,
                              hipStream_t stream) {
    const float* x    = (const float*)d_in[0];
    const float* Wih0 = (const float*)d_in[1];
    const float* Whh0 = (const float*)d_in[2];
    const float* bih0 = (const float*)d_in[3];
    const float* bhh0 = (const float*)d_in[4];
    const float* Wih1 = (const float*)d_in[5];
    const float* Whh1 = (const float*)d_in[6];
    const float* bih1 = (const float*)d_in[7];
    const float* bhh1 = (const float*)d_in[8];
    const float* Wlin = (const float*)d_in[9];
    const float* blin = (const float*)d_in[10];
    float* out = (float*)d_out;

    lstm2_kernel<<<NBLK, 256, 0, stream>>>(x, Wih0, Whh0, bih0, bhh0,
                                           Wih1, Whh1, bih1, bhh1,
                                           Wlin, blin, out);
}

// Round 11
// 806.774 us; speedup vs baseline: 4.2012x; 1.2143x over previous
//
#include <hip/hip_runtime.h>
#include <math.h>

#define Hn 50
#define Dn 8
#define Tn 512
#define BB 8              // batch rows per block (M-tile 16, rows 8..15 pad)
#define NBLK 256          // 2048 / BB
#define GP 260            // gLds row pad: 260 % 32 = 4 -> conflict-free r/w

typedef __attribute__((ext_vector_type(8))) short short8;   // 8 bf16 (4 VGPRs)
typedef __attribute__((ext_vector_type(4))) float f32x4;

__device__ __forceinline__ float fexp2_(float x) {
#if __has_builtin(__builtin_amdgcn_exp2f)
    return __builtin_amdgcn_exp2f(x);
#else
    return exp2f(x);
#endif
}
__device__ __forceinline__ float frcp_(float x) {
#if __has_builtin(__builtin_amdgcn_rcpf)
    return __builtin_amdgcn_rcpf(x);
#else
    return 1.0f / x;
#endif
}
__device__ __forceinline__ float sigmoidf_(float x) {
    return frcp_(1.0f + fexp2_(-1.44269504f * x));
}
__device__ __forceinline__ float tanhf_(float x) {
    return 2.0f * sigmoidf_(2.0f * x) - 1.0f;
}
__device__ __forceinline__ float bf2f(short s) {
    return __uint_as_float(((unsigned)(unsigned short)s) << 16);
}
// truncation split: v = hi + lo + O(2^-17 v)
__device__ __forceinline__ void split_bf(float v, short& hi, short& lo) {
    hi = (short)(__float_as_uint(v) >> 16);
    const float r = v - bf2f(hi);
    lo = (short)(__float_as_uint(r) >> 16);
}

// Persistent 2-layer LSTM on the matrix pipe.
// r10 was latency-exposed at 1 wave/SIMD (grid-limited occupancy 12%) and
// paid 5.9e7 LDS conflict cycles on gate reads (gLds row stride 256 == 0
// mod 32 banks -> batch index contributed nothing to the bank).
// r11: 512 threads (8 waves -> 2 waves/SIMD so one wave's LDS/MFMA latency
// hides under the other), 13 N-tiles spread 2/wave (w0-5:2, w6:1, w7:0 ->
// wave 7 stages x(t+1)), and gLds rows padded to 260 (4 mod 32) so both
// the D-stores and the f32x4 activation reads are bank-even.
// B-frags (96 regs/thread) feed ONLY MFMA -> AGPR-resident, copy-free;
// arch liveness ~70 fits the 8-wave 128-reg cap without spills.
// Layouts (m89/m120-verified): C/D n=lane&15, m=(lane>>4)*4+reg;
// A[m=lane&15][k=(lane>>4)*8+j]; B[k=(lane>>4)*8+j][n=lane&15].
__global__ __launch_bounds__(512, 1) void lstm2_kernel(
    const float* __restrict__ x,
    const float* __restrict__ Wih0, const float* __restrict__ Whh0,
    const float* __restrict__ bih0, const float* __restrict__ bhh0,
    const float* __restrict__ Wih1, const float* __restrict__ Whh1,
    const float* __restrict__ bih1, const float* __restrict__ bhh1,
    const float* __restrict__ Wlin, const float* __restrict__ blin,
    float* __restrict__ out)
{
    const int tid  = threadIdx.x;     // 0..511
    const int b0   = blockIdx.x * BB;
    const int w    = tid >> 6;        // wave 0..7
    const int lane = tid & 63;
    const int quad = lane >> 4;
    const int col  = lane & 15;
    const int ntw  = (w < 6) ? 2 : ((w == 6) ? 1 : 0);  // tiles this wave
    const int tb   = 2 * w;                              // tile base

    // A-packs (bf16 as short), inner dim padded 32->40.
    // idx(sg,s,m,k32) = ((sg*S+s)*16+m)*40+k32.
    // aP0: layer0 A = [h0 k0..49 | x k50..57 | 0], S=2.
    // aP1: layer1 A = [h0new k0..49 | 0 | h1 k64..113 | 0], S=4.
    __shared__ __align__(16) short aP0[2 * 2 * 16 * 40];
    __shared__ __align__(16) short aP1[2 * 4 * 16 * 40];
    __shared__ __align__(16) float gLds[8][GP];   // [m=batch][ng], 260-pad
    __shared__ float h1f[Hn * 8];                 // fp32 h1 at t=Tn-1

    // ---- B-fragments + bias in registers (cell-major columns) ----
    short8 B0[2][2][2];   // [tile][kstep][hi/lo]
    short8 B1[2][4][2];
    float  bw0[2], bw1[2];
    #pragma unroll
    for (int tt = 0; tt < 2; ++tt) {
        const int tile = tb + tt;
        const int ng = tile * 16 + col;            // cell-major gate column
        const int cl = ng >> 2, g = ng & 3;
        const bool on = (tt < ntw) && (cl < Hn);
        const int grow = g * Hn + cl;
        bw0[tt] = on ? (bih0[grow] + bhh0[grow]) : 0.f;
        bw1[tt] = on ? (bih1[grow] + bhh1[grow]) : 0.f;
        #pragma unroll
        for (int s = 0; s < 2; ++s)
            #pragma unroll
            for (int j = 0; j < 8; ++j) {
                const int k = 32 * s + quad * 8 + j;
                float v = 0.f;
                if (on) {
                    if (k < Hn)           v = Whh0[grow * Hn + k];
                    else if (k < Hn + Dn) v = Wih0[grow * Dn + (k - Hn)];
                }
                short hi, lo; split_bf(v, hi, lo);
                B0[tt][s][0][j] = hi; B0[tt][s][1][j] = lo;
            }
        #pragma unroll
        for (int s = 0; s < 4; ++s)
            #pragma unroll
            for (int j = 0; j < 8; ++j) {
                const int k = 32 * s + quad * 8 + j;
                float v = 0.f;
                if (on) {
                    if (k < Hn)                      v = Wih1[grow * Hn + k];
                    else if (k >= 64 && k < 64 + Hn) v = Whh1[grow * Hn + (k - 64)];
                }
                short hi, lo; split_bf(v, hi, lo);
                B1[tt][s][0][j] = hi; B1[tt][s][1][j] = lo;
            }
    }

    // ---- init: zero A-packs (pads must stay 0); stage x(t=0) ----
    for (int i = tid; i < 2 * 2 * 16 * 40; i += 512) aP0[i] = 0;
    for (int i = tid; i < 2 * 4 * 16 * 40; i += 512) aP1[i] = 0;
    __syncthreads();
    if (tid < 64) {
        const int xb = tid >> 3, xd = tid & 7;
        const float f = x[((size_t)(b0 + xb) * Tn + 0) * Dn + xd];
        short hi, lo; split_bf(f, hi, lo);
        aP0[((0 * 2 + 1) * 16 + xb) * 40 + 18 + xd] = hi;
        aP0[((1 * 2 + 1) * 16 + xb) * 40 + 18 + xd] = lo;
    }
    __syncthreads();

    // ---- activation ownership: tid<400 owns state (cell=tid>>3, b=tid&7) ----
    const int cA = tid >> 3, bA = tid & 7;
    const bool actT = (tid < Hn * 8);
    float c0 = 0.f, c1 = 0.f;

    for (int t = 0; t < Tn; ++t) {
        // ================= phase A: layer-0 MFMA =================
        if (ntw > 0) {
            f32x4 D0[2];
            #pragma unroll
            for (int tt = 0; tt < 2; ++tt) {
                f32x4 z = {bw0[tt], bw0[tt], bw0[tt], bw0[tt]};
                D0[tt] = z;
            }
            #pragma unroll
            for (int s = 0; s < 2; ++s) {
                const short8 ahi = *(const short8*)&aP0[((0*2+s)*16 + col)*40 + quad*8];
                const short8 alo = *(const short8*)&aP0[((1*2+s)*16 + col)*40 + quad*8];
                #pragma unroll
                for (int tt = 0; tt < 2; ++tt)
                    if (tt < ntw) {
                        D0[tt] = __builtin_amdgcn_mfma_f32_16x16x32_bf16(ahi, B0[tt][s][0], D0[tt], 0,0,0);
                        D0[tt] = __builtin_amdgcn_mfma_f32_16x16x32_bf16(ahi, B0[tt][s][1], D0[tt], 0,0,0);
                        D0[tt] = __builtin_amdgcn_mfma_f32_16x16x32_bf16(alo, B0[tt][s][0], D0[tt], 0,0,0);
                    }
            }
            if (quad < 2) {             // real rows m = quad*4+r in 0..7
                #pragma unroll
                for (int tt = 0; tt < 2; ++tt)
                    if (tt < ntw) {
                        const int n = (tb + tt) * 16 + col;
                        #pragma unroll
                        for (int r = 0; r < 4; ++r)
                            gLds[quad * 4 + r][n] = D0[tt][r];
                    }
            }
        }
        __syncthreads();

        // ================= phase B: layer-0 activations =================
        if (actT) {
            const f32x4 gv = *(const f32x4*)&gLds[bA][4 * cA];  // i,f,g,o
            c0 = sigmoidf_(gv.y) * c0 + sigmoidf_(gv.x) * tanhf_(gv.z);
            const float h = sigmoidf_(gv.w) * tanhf_(c0);
            short hi, lo; split_bf(h, hi, lo);
            const int s = cA >> 5, k32 = cA & 31;
            aP0[((0*2+s)*16 + bA)*40 + k32] = hi;
            aP0[((1*2+s)*16 + bA)*40 + k32] = lo;
            aP1[((0*4+s)*16 + bA)*40 + k32] = hi;
            aP1[((1*4+s)*16 + bA)*40 + k32] = lo;
        }
        __syncthreads();

        // ===== phase C: layer-1 MFMA; wave 7 stages x(t+1) =====
        if (ntw > 0) {
            f32x4 D1[2];
            #pragma unroll
            for (int tt = 0; tt < 2; ++tt) {
                f32x4 z = {bw1[tt], bw1[tt], bw1[tt], bw1[tt]};
                D1[tt] = z;
            }
            #pragma unroll
            for (int s = 0; s < 4; ++s) {
                const short8 ahi = *(const short8*)&aP1[((0*4+s)*16 + col)*40 + quad*8];
                const short8 alo = *(const short8*)&aP1[((1*4+s)*16 + col)*40 + quad*8];
                #pragma unroll
                for (int tt = 0; tt < 2; ++tt)
                    if (tt < ntw) {
                        D1[tt] = __builtin_amdgcn_mfma_f32_16x16x32_bf16(ahi, B1[tt][s][0], D1[tt], 0,0,0);
                        D1[tt] = __builtin_amdgcn_mfma_f32_16x16x32_bf16(ahi, B1[tt][s][1], D1[tt], 0,0,0);
                        D1[tt] = __builtin_amdgcn_mfma_f32_16x16x32_bf16(alo, B1[tt][s][0], D1[tt], 0,0,0);
                    }
            }
            if (quad < 2) {
                #pragma unroll
                for (int tt = 0; tt < 2; ++tt)
                    if (tt < ntw) {
                        const int n = (tb + tt) * 16 + col;
                        #pragma unroll
                        for (int r = 0; r < 4; ++r)
                            gLds[quad * 4 + r][n] = D1[tt][r];
                    }
            }
        } else if (t + 1 < Tn) {
            // wave 7: x(t+1) -> aP0 kstep1 slots (safe: phase A done reading)
            const int xb = lane >> 3, xd = lane & 7;
            const float f = x[((size_t)(b0 + xb) * Tn + (t + 1)) * Dn + xd];
            short hi, lo; split_bf(f, hi, lo);
            aP0[((0*2+1)*16 + xb)*40 + 18 + xd] = hi;
            aP0[((1*2+1)*16 + xb)*40 + 18 + xd] = lo;
        }
        __syncthreads();

        // ================= phase D: layer-1 activations =================
        if (actT) {
            const f32x4 gv = *(const f32x4*)&gLds[bA][4 * cA];
            c1 = sigmoidf_(gv.y) * c1 + sigmoidf_(gv.x) * tanhf_(gv.z);
            const float h = sigmoidf_(gv.w) * tanhf_(c1);
            short hi, lo; split_bf(h, hi, lo);
            const int s = 2 + (cA >> 5), k32 = cA & 31;     // k = 64 + cell
            aP1[((0*4+s)*16 + bA)*40 + k32] = hi;
            aP1[((1*4+s)*16 + bA)*40 + k32] = lo;
            if (t == Tn - 1) h1f[cA * 8 + bA] = h;
        }
        __syncthreads();
    }

    // ---- head: out[b] = h1_last . Wlin + blin (fp32 path) ----
    if (tid < BB) {
        float o = blin[0];
        #pragma unroll
        for (int k = 0; k < Hn; ++k) o += Wlin[k] * h1f[k * 8 + tid];
        out[b0 + tid] = o;
    }
}

extern "C" void kernel_launch(void* const* d_in, const int* in_sizes, int n_in,
                              void* d_out, int out_size, void* d_ws, size_t ws_size,
                              hipStream_t stream) {
    const float* x    = (const float*)d_in[0];
    const float* Wih0 = (const float*)d_in[1];
    const float* Whh0 = (const float*)d_in[2];
    const float* bih0 = (const float*)d_in[3];
    const float* bhh0 = (const float*)d_in[4];
    const float* Wih1 = (const float*)d_in[5];
    const float* Whh1 = (const float*)d_in[6];
    const float* bih1 = (const float*)d_in[7];
    const float* bhh1 = (const float*)d_in[8];
    const float* Wlin = (const float*)d_in[9];
    const float* blin = (const float*)d_in[10];
    float* out = (float*)d_out;

    lstm2_kernel<<<NBLK, 512, 0, stream>>>(x, Wih0, Whh0, bih0, bhh0,
                                           Wih1, Whh1, bih1, bhh1,
                                           Wlin, blin, out);
}

// Round 12
// 723.981 us; speedup vs baseline: 4.6817x; 1.1144x over previous
//
#include <hip/hip_runtime.h>
#include <math.h>

#define Hn 50
#define Dn 8
#define Tn 512
#define BB 8              // batch rows per block (M-tile 16, rows 8..15 pad)
#define NBLK 256          // 2048 / BB
#define GP 260            // gate-buffer row pad (floats)

typedef __attribute__((ext_vector_type(8))) short short8;   // 8 bf16 (4 VGPRs)
typedef __attribute__((ext_vector_type(4))) float f32x4;

__device__ __forceinline__ float fexp2_(float x) {
#if __has_builtin(__builtin_amdgcn_exp2f)
    return __builtin_amdgcn_exp2f(x);
#else
    return exp2f(x);
#endif
}
__device__ __forceinline__ float frcp_(float x) {
#if __has_builtin(__builtin_amdgcn_rcpf)
    return __builtin_amdgcn_rcpf(x);
#else
    return 1.0f / x;
#endif
}
__device__ __forceinline__ float sigmoidf_(float x) {
    return frcp_(1.0f + fexp2_(-1.44269504f * x));
}
__device__ __forceinline__ float tanhf_(float x) {
    return 2.0f * sigmoidf_(2.0f * x) - 1.0f;
}
__device__ __forceinline__ float bf2f(short s) {
    return __uint_as_float(((unsigned)(unsigned short)s) << 16);
}
// truncation split: v = hi + lo + O(2^-17 v)
__device__ __forceinline__ void split_bf(float v, short& hi, short& lo) {
    hi = (short)(__float_as_uint(v) >> 16);
    const float r = v - bf2f(hi);
    lo = (short)(__float_as_uint(r) >> 16);
}

// Persistent 2-layer LSTM, matrix pipe, SOFTWARE-PIPELINED 2-phase step.
// r11 (4 phases/step) had MFMA 27% + VALU 26% + LDS ~27% with near-zero
// overlap: the barrier structure serialized the pipes (3727 cyc/step vs
// ~1400 max-pipe). Key dependence: gates0(t) needs {h0(t-1), x(t)} and
// gates1(t-1) needs {h0(t-1), h1(t-2)} -> both computable in ONE phase.
// Step = [phase M: gates0(t) + gates1(t-1), 36 MFMA/wave]
//        [phase A: act1(t-1) then act0(t)], 2 barriers instead of 4.
// Prologue peels gates0(0)/act0(0); epilogue peels gates1(511)/act1(511).
// Wave 7 (no tiles, no act rows) loads x(t+1) in M, stores it in A.
// Layouts (m89/m120-verified): C/D n=lane&15, m=(lane>>4)*4+reg;
// A[m=lane&15][k=(lane>>4)*8+j]; B[k=(lane>>4)*8+j][n=lane&15].
__global__ __launch_bounds__(512, 1) void lstm2_kernel(
    const float* __restrict__ x,
    const float* __restrict__ Wih0, const float* __restrict__ Whh0,
    const float* __restrict__ bih0, const float* __restrict__ bhh0,
    const float* __restrict__ Wih1, const float* __restrict__ Whh1,
    const float* __restrict__ bih1, const float* __restrict__ bhh1,
    const float* __restrict__ Wlin, const float* __restrict__ blin,
    float* __restrict__ out)
{
    const int tid  = threadIdx.x;     // 0..511
    const int b0   = blockIdx.x * BB;
    const int w    = tid >> 6;        // wave 0..7
    const int lane = tid & 63;
    const int quad = lane >> 4;
    const int col  = lane & 15;
    const int ntw  = (w < 6) ? 2 : ((w == 6) ? 1 : 0);  // N-tiles this wave
    const int tb   = 2 * w;

    // A-packs (bf16 as short), inner dim padded 32->40.
    // aP0: layer0 A = [h0 k0..49 | x k50..57 | 0], S=2 ksteps.
    // aP1: layer1 A = [h0new k0..49 | 0 | h1 k64..113 | 0], S=4.
    __shared__ __align__(16) short aP0[2 * 2 * 16 * 40];
    __shared__ __align__(16) short aP1[2 * 4 * 16 * 40];
    __shared__ __align__(16) float gL[2][8][GP];  // [layer][m=batch][ng]
    __shared__ float h1f[Hn * 8];                 // fp32 h1 at t=Tn-1

    // ---- B-fragments + bias in registers (cell-major columns) ----
    short8 B0[2][2][2];   // [tile][kstep][hi/lo]
    short8 B1[2][4][2];
    float  bw0[2], bw1[2];
    #pragma unroll
    for (int tt = 0; tt < 2; ++tt) {
        const int ng = (tb + tt) * 16 + col;       // cell-major gate column
        const int cl = ng >> 2, g = ng & 3;
        const bool on = (tt < ntw) && (cl < Hn);
        const int grow = g * Hn + cl;
        bw0[tt] = on ? (bih0[grow] + bhh0[grow]) : 0.f;
        bw1[tt] = on ? (bih1[grow] + bhh1[grow]) : 0.f;
        #pragma unroll
        for (int s = 0; s < 2; ++s)
            #pragma unroll
            for (int j = 0; j < 8; ++j) {
                const int k = 32 * s + quad * 8 + j;
                float v = 0.f;
                if (on) {
                    if (k < Hn)           v = Whh0[grow * Hn + k];
                    else if (k < Hn + Dn) v = Wih0[grow * Dn + (k - Hn)];
                }
                short hi, lo; split_bf(v, hi, lo);
                B0[tt][s][0][j] = hi; B0[tt][s][1][j] = lo;
            }
        #pragma unroll
        for (int s = 0; s < 4; ++s)
            #pragma unroll
            for (int j = 0; j < 8; ++j) {
                const int k = 32 * s + quad * 8 + j;
                float v = 0.f;
                if (on) {
                    if (k < Hn)                      v = Wih1[grow * Hn + k];
                    else if (k >= 64 && k < 64 + Hn) v = Whh1[grow * Hn + (k - 64)];
                }
                short hi, lo; split_bf(v, hi, lo);
                B1[tt][s][0][j] = hi; B1[tt][s][1][j] = lo;
            }
    }

    // ---- init: zero A-packs (pads must stay 0); stage x(0) ----
    for (int i = tid; i < 2 * 2 * 16 * 40; i += 512) aP0[i] = 0;
    for (int i = tid; i < 2 * 4 * 16 * 40; i += 512) aP1[i] = 0;
    __syncthreads();
    if (tid < 64) {
        const int xb = tid >> 3, xd = tid & 7;
        const float f = x[((size_t)(b0 + xb) * Tn + 0) * Dn + xd];
        short hi, lo; split_bf(f, hi, lo);
        aP0[((0 * 2 + 1) * 16 + xb) * 40 + 18 + xd] = hi;
        aP0[((1 * 2 + 1) * 16 + xb) * 40 + 18 + xd] = lo;
    }
    __syncthreads();

    const int cA = tid >> 3, bA = tid & 7;
    const bool actT = (tid < Hn * 8);   // 400 act threads (waves 0..6)
    float c0 = 0.f, c1 = 0.f;
    float xreg = 0.f;                   // wave-7 x staging register

    // ============ prologue: gates0(0) ; act0(0) ============
    if (ntw > 0) {
        f32x4 D0[2];
        #pragma unroll
        for (int tt = 0; tt < 2; ++tt) {
            f32x4 z = {bw0[tt], bw0[tt], bw0[tt], bw0[tt]}; D0[tt] = z;
        }
        #pragma unroll
        for (int s = 0; s < 2; ++s) {
            const short8 ahi = *(const short8*)&aP0[((0*2+s)*16 + col)*40 + quad*8];
            const short8 alo = *(const short8*)&aP0[((1*2+s)*16 + col)*40 + quad*8];
            #pragma unroll
            for (int tt = 0; tt < 2; ++tt)
                if (tt < ntw) {
                    D0[tt] = __builtin_amdgcn_mfma_f32_16x16x32_bf16(ahi, B0[tt][s][0], D0[tt], 0,0,0);
                    D0[tt] = __builtin_amdgcn_mfma_f32_16x16x32_bf16(ahi, B0[tt][s][1], D0[tt], 0,0,0);
                    D0[tt] = __builtin_amdgcn_mfma_f32_16x16x32_bf16(alo, B0[tt][s][0], D0[tt], 0,0,0);
                }
        }
        if (quad < 2) {
            #pragma unroll
            for (int tt = 0; tt < 2; ++tt)
                if (tt < ntw) {
                    const int n = (tb + tt) * 16 + col;
                    #pragma unroll
                    for (int r = 0; r < 4; ++r) gL[0][quad * 4 + r][n] = D0[tt][r];
                }
        }
    } else {
        xreg = x[((size_t)(b0 + (lane >> 3)) * Tn + 1) * Dn + (lane & 7)];
    }
    __syncthreads();
    if (actT) {
        const f32x4 gv = *(const f32x4*)&gL[0][bA][4 * cA];
        c0 = sigmoidf_(gv.y) * c0 + sigmoidf_(gv.x) * tanhf_(gv.z);
        const float h = sigmoidf_(gv.w) * tanhf_(c0);
        short hi, lo; split_bf(h, hi, lo);
        const int s = cA >> 5, k32 = cA & 31;
        aP0[((0*2+s)*16 + bA)*40 + k32] = hi;
        aP0[((1*2+s)*16 + bA)*40 + k32] = lo;
        aP1[((0*4+s)*16 + bA)*40 + k32] = hi;
        aP1[((1*4+s)*16 + bA)*40 + k32] = lo;
    } else if (w == 7) {
        short hi, lo; split_bf(xreg, hi, lo);
        aP0[((0*2+1)*16 + (lane >> 3))*40 + 18 + (lane & 7)] = hi;
        aP0[((1*2+1)*16 + (lane >> 3))*40 + 18 + (lane & 7)] = lo;
    }
    __syncthreads();

    // ============ main loop: t = 1 .. Tn-1 ============
    for (int t = 1; t < Tn; ++t) {
        // ---- phase M: gates0(t) + gates1(t-1) in one MFMA burst ----
        if (ntw > 0) {
            f32x4 D0[2], D1[2];
            #pragma unroll
            for (int tt = 0; tt < 2; ++tt) {
                f32x4 z0 = {bw0[tt], bw0[tt], bw0[tt], bw0[tt]}; D0[tt] = z0;
                f32x4 z1 = {bw1[tt], bw1[tt], bw1[tt], bw1[tt]}; D1[tt] = z1;
            }
            #pragma unroll
            for (int s = 0; s < 2; ++s) {
                const short8 ahi = *(const short8*)&aP0[((0*2+s)*16 + col)*40 + quad*8];
                const short8 alo = *(const short8*)&aP0[((1*2+s)*16 + col)*40 + quad*8];
                #pragma unroll
                for (int tt = 0; tt < 2; ++tt)
                    if (tt < ntw) {
                        D0[tt] = __builtin_amdgcn_mfma_f32_16x16x32_bf16(ahi, B0[tt][s][0], D0[tt], 0,0,0);
                        D0[tt] = __builtin_amdgcn_mfma_f32_16x16x32_bf16(ahi, B0[tt][s][1], D0[tt], 0,0,0);
                        D0[tt] = __builtin_amdgcn_mfma_f32_16x16x32_bf16(alo, B0[tt][s][0], D0[tt], 0,0,0);
                    }
            }
            #pragma unroll
            for (int s = 0; s < 4; ++s) {
                const short8 ahi = *(const short8*)&aP1[((0*4+s)*16 + col)*40 + quad*8];
                const short8 alo = *(const short8*)&aP1[((1*4+s)*16 + col)*40 + quad*8];
                #pragma unroll
                for (int tt = 0; tt < 2; ++tt)
                    if (tt < ntw) {
                        D1[tt] = __builtin_amdgcn_mfma_f32_16x16x32_bf16(ahi, B1[tt][s][0], D1[tt], 0,0,0);
                        D1[tt] = __builtin_amdgcn_mfma_f32_16x16x32_bf16(ahi, B1[tt][s][1], D1[tt], 0,0,0);
                        D1[tt] = __builtin_amdgcn_mfma_f32_16x16x32_bf16(alo, B1[tt][s][0], D1[tt], 0,0,0);
                    }
            }
            if (quad < 2) {
                #pragma unroll
                for (int tt = 0; tt < 2; ++tt)
                    if (tt < ntw) {
                        const int n = (tb + tt) * 16 + col;
                        #pragma unroll
                        for (int r = 0; r < 4; ++r) {
                            gL[0][quad * 4 + r][n] = D0[tt][r];
                            gL[1][quad * 4 + r][n] = D1[tt][r];
                        }
                    }
            }
        } else {
            const int tn = (t + 1 < Tn) ? (t + 1) : (Tn - 1);
            xreg = x[((size_t)(b0 + (lane >> 3)) * Tn + tn) * Dn + (lane & 7)];
        }
        __syncthreads();

        // ---- phase A: act1(t-1) then act0(t); wave 7 stages x(t+1) ----
        if (actT) {
            {   // layer-1 activation for step t-1
                const f32x4 gv = *(const f32x4*)&gL[1][bA][4 * cA];
                c1 = sigmoidf_(gv.y) * c1 + sigmoidf_(gv.x) * tanhf_(gv.z);
                const float h = sigmoidf_(gv.w) * tanhf_(c1);
                short hi, lo; split_bf(h, hi, lo);
                const int s = 2 + (cA >> 5), k32 = cA & 31;   // k = 64+cell
                aP1[((0*4+s)*16 + bA)*40 + k32] = hi;
                aP1[((1*4+s)*16 + bA)*40 + k32] = lo;
            }
            {   // layer-0 activation for step t
                const f32x4 gv = *(const f32x4*)&gL[0][bA][4 * cA];
                c0 = sigmoidf_(gv.y) * c0 + sigmoidf_(gv.x) * tanhf_(gv.z);
                const float h = sigmoidf_(gv.w) * tanhf_(c0);
                short hi, lo; split_bf(h, hi, lo);
                const int s = cA >> 5, k32 = cA & 31;
                aP0[((0*2+s)*16 + bA)*40 + k32] = hi;
                aP0[((1*2+s)*16 + bA)*40 + k32] = lo;
                aP1[((0*4+s)*16 + bA)*40 + k32] = hi;
                aP1[((1*4+s)*16 + bA)*40 + k32] = lo;
            }
        } else if (w == 7) {
            short hi, lo; split_bf(xreg, hi, lo);
            aP0[((0*2+1)*16 + (lane >> 3))*40 + 18 + (lane & 7)] = hi;
            aP0[((1*2+1)*16 + (lane >> 3))*40 + 18 + (lane & 7)] = lo;
        }
        __syncthreads();
    }

    // ============ epilogue: gates1(Tn-1) ; act1(Tn-1) ============
    if (ntw > 0) {
        f32x4 D1[2];
        #pragma unroll
        for (int tt = 0; tt < 2; ++tt) {
            f32x4 z = {bw1[tt], bw1[tt], bw1[tt], bw1[tt]}; D1[tt] = z;
        }
        #pragma unroll
        for (int s = 0; s < 4; ++s) {
            const short8 ahi = *(const short8*)&aP1[((0*4+s)*16 + col)*40 + quad*8];
            const short8 alo = *(const short8*)&aP1[((1*4+s)*16 + col)*40 + quad*8];
            #pragma unroll
            for (int tt = 0; tt < 2; ++tt)
                if (tt < ntw) {
                    D1[tt] = __builtin_amdgcn_mfma_f32_16x16x32_bf16(ahi, B1[tt][s][0], D1[tt], 0,0,0);
                    D1[tt] = __builtin_amdgcn_mfma_f32_16x16x32_bf16(ahi, B1[tt][s][1], D1[tt], 0,0,0);
                    D1[tt] = __builtin_amdgcn_mfma_f32_16x16x32_bf16(alo, B1[tt][s][0], D1[tt], 0,0,0);
                }
        }
        if (quad < 2) {
            #pragma unroll
            for (int tt = 0; tt < 2; ++tt)
                if (tt < ntw) {
                    const int n = (tb + tt) * 16 + col;
                    #pragma unroll
                    for (int r = 0; r < 4; ++r) gL[1][quad * 4 + r][n] = D1[tt][r];
                }
        }
    }
    __syncthreads();
    if (actT) {
        const f32x4 gv = *(const f32x4*)&gL[1][bA][4 * cA];
        c1 = sigmoidf_(gv.y) * c1 + sigmoidf_(gv.x) * tanhf_(gv.z);
        h1f[cA * 8 + bA] = sigmoidf_(gv.w) * tanhf_(c1);
    }
    __syncthreads();

    // ---- head: out[b] = h1_last . Wlin + blin (fp32 path) ----
    if (tid < BB) {
        float o = blin[0];
        #pragma unroll
        for (int k = 0; k < Hn; ++k) o += Wlin[k] * h1f[k * 8 + tid];
        out[b0 + tid] = o;
    }
}

extern "C" void kernel_launch(void* const* d_in, const int* in_sizes, int n_in,
                              void* d_out, int out_size, void* d_ws, size_t ws_size,
                              hipStream_t stream) {
    const float* x    = (const float*)d_in[0];
    const float* Wih0 = (const float*)d_in[1];
    const float* Whh0 = (const float*)d_in[2];
    const float* bih0 = (const float*)d_in[3];
    const float* bhh0 = (const float*)d_in[4];
    const float* Wih1 = (const float*)d_in[5];
    const float* Whh1 = (const float*)d_in[6];
    const float* bih1 = (const float*)d_in[7];
    const float* bhh1 = (const float*)d_in[8];
    const float* Wlin = (const float*)d_in[9];
    const float* blin = (const float*)d_in[10];
    float* out = (float*)d_out;

    lstm2_kernel<<<NBLK, 512, 0, stream>>>(x, Wih0, Whh0, bih0, bhh0,
                                           Wih1, Whh1, bih1, bhh1,
                                           Wlin, blin, out);
}

// Round 13
// 705.035 us; speedup vs baseline: 4.8075x; 1.0269x over previous
//
#include <hip/hip_runtime.h>
#include <math.h>

#define Hn 50
#define Dn 8
#define Tn 512
#define BB 8              // batch rows per block (M-tile 16, rows 8..15 pad)
#define NBLK 256          // 2048 / BB
#define GP 260            // gate-buffer row pad (floats)

typedef __attribute__((ext_vector_type(8))) short short8;   // 8 bf16 (4 VGPRs)
typedef __attribute__((ext_vector_type(4))) float f32x4;

__device__ __forceinline__ float fexp2_(float x) {
#if __has_builtin(__builtin_amdgcn_exp2f)
    return __builtin_amdgcn_exp2f(x);
#else
    return exp2f(x);
#endif
}
__device__ __forceinline__ float frcp_(float x) {
#if __has_builtin(__builtin_amdgcn_rcpf)
    return __builtin_amdgcn_rcpf(x);
#else
    return 1.0f / x;
#endif
}
__device__ __forceinline__ float sigmoidf_(float x) {
    return frcp_(1.0f + fexp2_(-1.44269504f * x));
}
__device__ __forceinline__ float tanhf_(float x) {
    return 2.0f * sigmoidf_(2.0f * x) - 1.0f;
}
__device__ __forceinline__ float bf2f(short s) {
    return __uint_as_float(((unsigned)(unsigned short)s) << 16);
}
// truncation split: v = hi + lo + O(2^-17 v)
__device__ __forceinline__ void split_bf(float v, short& hi, short& lo) {
    hi = (short)(__float_as_uint(v) >> 16);
    const float r = v - bf2f(hi);
    lo = (short)(__float_as_uint(r) >> 16);
}

// Persistent 2-layer LSTM, matrix pipe, 2-phase pipelined step (r12) with a
// SHARED A-pack: r12's aP1 k0..49 duplicated aP0's h0 — both layers now read
// the same [h0|x] fragments (B1's x-columns are zero, so x contributes 0 to
// layer-1 gates). A-frag reads drop 12 -> 8 b128/wave/step, act0 writes
// 4 -> 2. Layer-1's 12-MFMA accumulation chain is split into two 6-chains
// (D1a: shared ksteps, D1b: h1 ksteps) merged by one f32x4 add, halving the
// dependency depth the 2 waves/SIMD must hide.
// A-pack aPS[p=hi/lo][s=0..3][m=16][k32=40]:
//   s0:   h0 cells 0..31
//   s1:   h0 cells 32..49 | x d0..7 (k32 18..25) | 0
//   s2:   h1 cells 0..31
//   s3:   h1 cells 32..49 | 0
// Layouts (m89/m120-verified): C/D n=lane&15, m=(lane>>4)*4+reg;
// A[m=lane&15][k=(lane>>4)*8+j]; B[k=(lane>>4)*8+j][n=lane&15].
__global__ __launch_bounds__(512, 1) void lstm2_kernel(
    const float* __restrict__ x,
    const float* __restrict__ Wih0, const float* __restrict__ Whh0,
    const float* __restrict__ bih0, const float* __restrict__ bhh0,
    const float* __restrict__ Wih1, const float* __restrict__ Whh1,
    const float* __restrict__ bih1, const float* __restrict__ bhh1,
    const float* __restrict__ Wlin, const float* __restrict__ blin,
    float* __restrict__ out)
{
    const int tid  = threadIdx.x;     // 0..511
    const int b0   = blockIdx.x * BB;
    const int w    = tid >> 6;        // wave 0..7
    const int lane = tid & 63;
    const int quad = lane >> 4;
    const int col  = lane & 15;
    const int ntw  = (w < 6) ? 2 : ((w == 6) ? 1 : 0);  // N-tiles this wave
    const int tb   = 2 * w;

    __shared__ __align__(16) short aPS[2 * 4 * 16 * 40];  // shared A-pack
    __shared__ __align__(16) float gL[2][8][GP];  // [layer][m=batch][ng]
    __shared__ float h1f[Hn * 8];                 // fp32 h1 at t=Tn-1

    // ---- B-fragments + bias in registers (cell-major columns) ----
    short8 B0[2][2][2];   // [tile][kstep][hi/lo]  (shared ksteps 0..1)
    short8 B1[2][4][2];   // [tile][kstep][hi/lo]  (s0,1 = Wih1; s2,3 = Whh1)
    float  bw0[2], bw1[2];
    #pragma unroll
    for (int tt = 0; tt < 2; ++tt) {
        const int ng = (tb + tt) * 16 + col;       // cell-major gate column
        const int cl = ng >> 2, g = ng & 3;
        const bool on = (tt < ntw) && (cl < Hn);
        const int grow = g * Hn + cl;
        bw0[tt] = on ? (bih0[grow] + bhh0[grow]) : 0.f;
        bw1[tt] = on ? (bih1[grow] + bhh1[grow]) : 0.f;
        #pragma unroll
        for (int s = 0; s < 2; ++s)
            #pragma unroll
            for (int j = 0; j < 8; ++j) {
                const int k = 32 * s + quad * 8 + j;
                float v = 0.f;
                if (on) {
                    if (k < Hn)           v = Whh0[grow * Hn + k];
                    else if (k < Hn + Dn) v = Wih0[grow * Dn + (k - Hn)];
                }
                short hi, lo; split_bf(v, hi, lo);
                B0[tt][s][0][j] = hi; B0[tt][s][1][j] = lo;
            }
        #pragma unroll
        for (int s = 0; s < 4; ++s)
            #pragma unroll
            for (int j = 0; j < 8; ++j) {
                const int k = 32 * s + quad * 8 + j;
                float v = 0.f;
                if (on) {
                    if (k < Hn)                      v = Wih1[grow * Hn + k];
                    else if (k >= 64 && k < 64 + Hn) v = Whh1[grow * Hn + (k - 64)];
                    // k 50..63: zero -> shared-pack x columns contribute 0
                }
                short hi, lo; split_bf(v, hi, lo);
                B1[tt][s][0][j] = hi; B1[tt][s][1][j] = lo;
            }
    }

    // ---- init: zero A-pack (pads must stay 0); stage x(0) ----
    for (int i = tid; i < 2 * 4 * 16 * 40; i += 512) aPS[i] = 0;
    __syncthreads();
    if (tid < 64) {
        const int xb = tid >> 3, xd = tid & 7;
        const float f = x[((size_t)(b0 + xb) * Tn + 0) * Dn + xd];
        short hi, lo; split_bf(f, hi, lo);
        aPS[((0 * 4 + 1) * 16 + xb) * 40 + 18 + xd] = hi;
        aPS[((1 * 4 + 1) * 16 + xb) * 40 + 18 + xd] = lo;
    }
    __syncthreads();

    const int cA = tid >> 3, bA = tid & 7;
    const bool actT = (tid < Hn * 8);   // 400 act threads (waves 0..6)
    float c0 = 0.f, c1 = 0.f;
    float xreg = 0.f;                   // wave-7 x staging register

    // ============ prologue: gates0(0) ; act0(0) ============
    if (ntw > 0) {
        f32x4 D0[2];
        #pragma unroll
        for (int tt = 0; tt < 2; ++tt) {
            f32x4 z = {bw0[tt], bw0[tt], bw0[tt], bw0[tt]}; D0[tt] = z;
        }
        #pragma unroll
        for (int s = 0; s < 2; ++s) {
            const short8 ahi = *(const short8*)&aPS[((0*4+s)*16 + col)*40 + quad*8];
            const short8 alo = *(const short8*)&aPS[((1*4+s)*16 + col)*40 + quad*8];
            #pragma unroll
            for (int tt = 0; tt < 2; ++tt)
                if (tt < ntw) {
                    D0[tt] = __builtin_amdgcn_mfma_f32_16x16x32_bf16(ahi, B0[tt][s][0], D0[tt], 0,0,0);
                    D0[tt] = __builtin_amdgcn_mfma_f32_16x16x32_bf16(ahi, B0[tt][s][1], D0[tt], 0,0,0);
                    D0[tt] = __builtin_amdgcn_mfma_f32_16x16x32_bf16(alo, B0[tt][s][0], D0[tt], 0,0,0);
                }
        }
        if (quad < 2) {
            #pragma unroll
            for (int tt = 0; tt < 2; ++tt)
                if (tt < ntw) {
                    const int n = (tb + tt) * 16 + col;
                    #pragma unroll
                    for (int r = 0; r < 4; ++r) gL[0][quad * 4 + r][n] = D0[tt][r];
                }
        }
    } else {
        xreg = x[((size_t)(b0 + (lane >> 3)) * Tn + 1) * Dn + (lane & 7)];
    }
    __syncthreads();
    if (actT) {
        const f32x4 gv = *(const f32x4*)&gL[0][bA][4 * cA];
        c0 = sigmoidf_(gv.y) * c0 + sigmoidf_(gv.x) * tanhf_(gv.z);
        const float h = sigmoidf_(gv.w) * tanhf_(c0);
        short hi, lo; split_bf(h, hi, lo);
        const int s = cA >> 5, k32 = cA & 31;
        aPS[((0*4+s)*16 + bA)*40 + k32] = hi;
        aPS[((1*4+s)*16 + bA)*40 + k32] = lo;
    } else if (w == 7) {
        short hi, lo; split_bf(xreg, hi, lo);
        aPS[((0*4+1)*16 + (lane >> 3))*40 + 18 + (lane & 7)] = hi;
        aPS[((1*4+1)*16 + (lane >> 3))*40 + 18 + (lane & 7)] = lo;
    }
    __syncthreads();

    // ============ main loop: t = 1 .. Tn-1 ============
    for (int t = 1; t < Tn; ++t) {
        // ---- phase M: gates0(t) + gates1(t-1), shared A-frags ----
        if (ntw > 0) {
            f32x4 D0[2], D1a[2], D1b[2];
            #pragma unroll
            for (int tt = 0; tt < 2; ++tt) {
                f32x4 z0 = {bw0[tt], bw0[tt], bw0[tt], bw0[tt]}; D0[tt]  = z0;
                f32x4 z1 = {bw1[tt], bw1[tt], bw1[tt], bw1[tt]}; D1a[tt] = z1;
                f32x4 zz = {0.f, 0.f, 0.f, 0.f};                 D1b[tt] = zz;
            }
            #pragma unroll
            for (int s = 0; s < 2; ++s) {       // shared [h0|x] ksteps
                const short8 ahi = *(const short8*)&aPS[((0*4+s)*16 + col)*40 + quad*8];
                const short8 alo = *(const short8*)&aPS[((1*4+s)*16 + col)*40 + quad*8];
                #pragma unroll
                for (int tt = 0; tt < 2; ++tt)
                    if (tt < ntw) {
                        D0[tt]  = __builtin_amdgcn_mfma_f32_16x16x32_bf16(ahi, B0[tt][s][0], D0[tt],  0,0,0);
                        D0[tt]  = __builtin_amdgcn_mfma_f32_16x16x32_bf16(ahi, B0[tt][s][1], D0[tt],  0,0,0);
                        D0[tt]  = __builtin_amdgcn_mfma_f32_16x16x32_bf16(alo, B0[tt][s][0], D0[tt],  0,0,0);
                        D1a[tt] = __builtin_amdgcn_mfma_f32_16x16x32_bf16(ahi, B1[tt][s][0], D1a[tt], 0,0,0);
                        D1a[tt] = __builtin_amdgcn_mfma_f32_16x16x32_bf16(ahi, B1[tt][s][1], D1a[tt], 0,0,0);
                        D1a[tt] = __builtin_amdgcn_mfma_f32_16x16x32_bf16(alo, B1[tt][s][0], D1a[tt], 0,0,0);
                    }
            }
            #pragma unroll
            for (int s = 2; s < 4; ++s) {       // h1 ksteps
                const short8 ahi = *(const short8*)&aPS[((0*4+s)*16 + col)*40 + quad*8];
                const short8 alo = *(const short8*)&aPS[((1*4+s)*16 + col)*40 + quad*8];
                #pragma unroll
                for (int tt = 0; tt < 2; ++tt)
                    if (tt < ntw) {
                        D1b[tt] = __builtin_amdgcn_mfma_f32_16x16x32_bf16(ahi, B1[tt][s][0], D1b[tt], 0,0,0);
                        D1b[tt] = __builtin_amdgcn_mfma_f32_16x16x32_bf16(ahi, B1[tt][s][1], D1b[tt], 0,0,0);
                        D1b[tt] = __builtin_amdgcn_mfma_f32_16x16x32_bf16(alo, B1[tt][s][0], D1b[tt], 0,0,0);
                    }
            }
            if (quad < 2) {
                #pragma unroll
                for (int tt = 0; tt < 2; ++tt)
                    if (tt < ntw) {
                        const int n = (tb + tt) * 16 + col;
                        #pragma unroll
                        for (int r = 0; r < 4; ++r) {
                            gL[0][quad * 4 + r][n] = D0[tt][r];
                            gL[1][quad * 4 + r][n] = D1a[tt][r] + D1b[tt][r];
                        }
                    }
            }
        } else {
            const int tn = (t + 1 < Tn) ? (t + 1) : (Tn - 1);
            xreg = x[((size_t)(b0 + (lane >> 3)) * Tn + tn) * Dn + (lane & 7)];
        }
        __syncthreads();

        // ---- phase A: act1(t-1) then act0(t); wave 7 stages x(t+1) ----
        if (actT) {
            {   // layer-1 activation for step t-1 -> h1 region (s2,s3)
                const f32x4 gv = *(const f32x4*)&gL[1][bA][4 * cA];
                c1 = sigmoidf_(gv.y) * c1 + sigmoidf_(gv.x) * tanhf_(gv.z);
                const float h = sigmoidf_(gv.w) * tanhf_(c1);
                short hi, lo; split_bf(h, hi, lo);
                const int s = 2 + (cA >> 5), k32 = cA & 31;
                aPS[((0*4+s)*16 + bA)*40 + k32] = hi;
                aPS[((1*4+s)*16 + bA)*40 + k32] = lo;
            }
            {   // layer-0 activation for step t -> shared region (s0,s1)
                const f32x4 gv = *(const f32x4*)&gL[0][bA][4 * cA];
                c0 = sigmoidf_(gv.y) * c0 + sigmoidf_(gv.x) * tanhf_(gv.z);
                const float h = sigmoidf_(gv.w) * tanhf_(c0);
                short hi, lo; split_bf(h, hi, lo);
                const int s = cA >> 5, k32 = cA & 31;
                aPS[((0*4+s)*16 + bA)*40 + k32] = hi;
                aPS[((1*4+s)*16 + bA)*40 + k32] = lo;
            }
        } else if (w == 7) {
            short hi, lo; split_bf(xreg, hi, lo);
            aPS[((0*4+1)*16 + (lane >> 3))*40 + 18 + (lane & 7)] = hi;
            aPS[((1*4+1)*16 + (lane >> 3))*40 + 18 + (lane & 7)] = lo;
        }
        __syncthreads();
    }

    // ============ epilogue: gates1(Tn-1) ; act1(Tn-1) ============
    if (ntw > 0) {
        f32x4 D1a[2], D1b[2];
        #pragma unroll
        for (int tt = 0; tt < 2; ++tt) {
            f32x4 z = {bw1[tt], bw1[tt], bw1[tt], bw1[tt]}; D1a[tt] = z;
            f32x4 zz = {0.f, 0.f, 0.f, 0.f};                D1b[tt] = zz;
        }
        #pragma unroll
        for (int s = 0; s < 4; ++s) {
            const short8 ahi = *(const short8*)&aPS[((0*4+s)*16 + col)*40 + quad*8];
            const short8 alo = *(const short8*)&aPS[((1*4+s)*16 + col)*40 + quad*8];
            #pragma unroll
            for (int tt = 0; tt < 2; ++tt)
                if (tt < ntw) {
                    f32x4& D = (s < 2) ? D1a[tt] : D1b[tt];
                    D = __builtin_amdgcn_mfma_f32_16x16x32_bf16(ahi, B1[tt][s][0], D, 0,0,0);
                    D = __builtin_amdgcn_mfma_f32_16x16x32_bf16(ahi, B1[tt][s][1], D, 0,0,0);
                    D = __builtin_amdgcn_mfma_f32_16x16x32_bf16(alo, B1[tt][s][0], D, 0,0,0);
                }
        }
        if (quad < 2) {
            #pragma unroll
            for (int tt = 0; tt < 2; ++tt)
                if (tt < ntw) {
                    const int n = (tb + tt) * 16 + col;
                    #pragma unroll
                    for (int r = 0; r < 4; ++r)
                        gL[1][quad * 4 + r][n] = D1a[tt][r] + D1b[tt][r];
                }
        }
    }
    __syncthreads();
    if (actT) {
        const f32x4 gv = *(const f32x4*)&gL[1][bA][4 * cA];
        c1 = sigmoidf_(gv.y) * c1 + sigmoidf_(gv.x) * tanhf_(gv.z);
        h1f[cA * 8 + bA] = sigmoidf_(gv.w) * tanhf_(c1);
    }
    __syncthreads();

    // ---- head: out[b] = h1_last . Wlin + blin (fp32 path) ----
    if (tid < BB) {
        float o = blin[0];
        #pragma unroll
        for (int k = 0; k < Hn; ++k) o += Wlin[k] * h1f[k * 8 + tid];
        out[b0 + tid] = o;
    }
}

extern "C" void kernel_launch(void* const* d_in, const int* in_sizes, int n_in,
                              void* d_out, int out_size, void* d_ws, size_t ws_size,
                              hipStream_t stream) {
    const float* x    = (const float*)d_in[0];
    const float* Wih0 = (const float*)d_in[1];
    const float* Whh0 = (const float*)d_in[2];
    const float* bih0 = (const float*)d_in[3];
    const float* bhh0 = (const float*)d_in[4];
    const float* Wih1 = (const float*)d_in[5];
    const float* Whh1 = (const float*)d_in[6];
    const float* bih1 = (const float*)d_in[7];
    const float* bhh1 = (const float*)d_in[8];
    const float* Wlin = (const float*)d_in[9];
    const float* blin = (const float*)d_in[10];
    float* out = (float*)d_out;

    lstm2_kernel<<<NBLK, 512, 0, stream>>>(x, Wih0, Whh0, bih0, bhh0,
                                           Wih1, Whh1, bih1, bhh1,
                                           Wlin, blin, out);
}